// Round 10
// baseline (540.417 us; speedup 1.0000x reference)
//
#include <hip/hip_runtime.h>
#include <math.h>

#define B 4
#define C 56
#define H 320
#define W 320
#define HC 313
#define WC 313
#define NIMG (H*W)          // 102400
#define NSP  (HC*WC)        // 97969
#define NPIX (B*NSP)        // 391876
#define NM   (B*NIMG)       // 409600
#define BN_EPS 1e-5f
#define NCHUNK3 3062        // ceil(NPIX/128): one block per chunk, no loops

// pool32 tile: 32x32 interior, 39x39 halo
#define PHR 39
#define PNH (PHR*PHR)       // 1521

typedef __attribute__((ext_vector_type(8))) short short8;
typedef __attribute__((ext_vector_type(16))) float float16;

__device__ __forceinline__ unsigned short f2bf(float v) {
  unsigned int u = __float_as_uint(v);
  return (unsigned short)((u + 0x7fffu + ((u >> 16) & 1u)) >> 16);
}

// ---------------------------------------------------------------------------
// pool32 (R5-verified, verbatim): one (32x32 tile, b, 8-ch group) per block.
// p_t layout: [g][pix 0..NPIX)[8 ch] bf16, pix = b*NSP + gi*WC + gj (dense).
// ---------------------------------------------------------------------------
__global__ __launch_bounds__(256) void pool32_kernel(
    const float* __restrict__ x, float* __restrict__ Epart,
    unsigned short* __restrict__ p_t) {
  __shared__ float tin[PHR][40];
  __shared__ float hs[PHR][32];
  __shared__ unsigned short Pt[8][1024];
  const int tid = threadIdx.x;
  int bid = blockIdx.x;
  const int g = bid % 7; bid /= 7;
  const int b = bid & 3; bid >>= 2;
  const int ty = bid / 10, tx = bid - (bid / 10) * 10;
  const int i0 = ty * 32, j0 = tx * 32;
  const float* xg = x + ((size_t)b * C + g * 8) * NIMG;

  float esum[6];
  #pragma unroll
  for (int k = 0; k < 6; ++k) esum[k] = 0.f;

  float cur[6], nxt[6];
  {
    const float* xp = xg;
    #pragma unroll
    for (int k = 0; k < 6; ++k) {
      int idx = tid + k * 256;
      int r = idx / PHR, cc = idx - r * PHR;
      int gi = i0 + r, gj = j0 + cc;
      cur[k] = (idx < PNH && gi < H && gj < W) ? xp[gi * W + gj] : 0.f;
    }
  }

  #pragma unroll
  for (int c = 0; c < 8; ++c) {
    #pragma unroll
    for (int k = 0; k < 6; ++k) {
      int idx = tid + k * 256;
      if (idx < PNH) {
        int r = idx / PHR, cc = idx - r * PHR;
        tin[r][cc] = cur[k];
        if (r < 32 && cc < 32) esum[k] += cur[k];
      }
    }
    __syncthreads();
    if (c < 7) {
      const float* xp = xg + (size_t)(c + 1) * NIMG;
      #pragma unroll
      for (int k = 0; k < 6; ++k) {
        int idx = tid + k * 256;
        int r = idx / PHR, cc = idx - r * PHR;
        int gi = i0 + r, gj = j0 + cc;
        nxt[k] = (idx < PNH && gi < H && gj < W) ? xp[gi * W + gj] : 0.f;
      }
    }
    #pragma unroll
    for (int it = 0; it < 5; ++it) {
      int idx = tid + it * 256;
      if (idx < PHR * 32) {
        int r = idx >> 5, j = idx & 31;
        float s = 0.f;
        #pragma unroll
        for (int d = 0; d < 8; ++d) s += tin[r][j + d];
        hs[r][j] = s;
      }
    }
    __syncthreads();
    #pragma unroll
    for (int it = 0; it < 4; ++it) {
      int idx = tid + it * 256;
      int i = idx >> 5, j = idx & 31;
      float s = 0.f;
      #pragma unroll
      for (int d = 0; d < 8; ++d) s += hs[i + d][j];
      Pt[c][idx] = f2bf(s * (1.f / 64.f));
    }
    #pragma unroll
    for (int k = 0; k < 6; ++k) cur[k] = nxt[k];
  }
  __syncthreads();   // Pt complete

  float* Eb = Epart + ((size_t)g * B + b) * NIMG;
  #pragma unroll
  for (int k = 0; k < 6; ++k) {
    int idx = tid + k * 256;
    if (idx < PNH) {
      int r = idx / PHR, cc = idx - r * PHR;
      if (r < 32 && cc < 32) Eb[(i0 + r) * W + (j0 + cc)] = esum[k];
    }
  }

  unsigned short* pg = p_t + (size_t)g * NPIX * 8;
  #pragma unroll
  for (int k = 0; k < 4; ++k) {
    int idx = tid + k * 256;
    int i = idx >> 5, j = idx & 31;
    int gi = i0 + i, gj = j0 + j;
    if (gi < HC && gj < WC) {
      unsigned short t8[8];
      #pragma unroll
      for (int c2 = 0; c2 < 8; ++c2) t8[c2] = Pt[c2][idx];
      *(short8*)(pg + ((size_t)b * NSP + gi * WC + gj) * 8) = *(short8*)t8;
    }
  }
}

// ---------------------------------------------------------------------------
// se_pool (R5-verified, verbatim)
// ---------------------------------------------------------------------------
__global__ __launch_bounds__(256) void se_pool_kernel(
    const float* __restrict__ Epart, float* __restrict__ E, float* __restrict__ S) {
  __shared__ float tin[39][40];
  __shared__ float hs[39][33];
  const int b = blockIdx.z;
  const int i0 = blockIdx.y * 32, j0 = blockIdx.x * 32;
  const int tid = threadIdx.x;
  for (int idx = tid; idx < 39 * 39; idx += 256) {
    int r = idx / 39, cc = idx - r * 39;
    int gi = i0 + r, gj = j0 + cc;
    float v = 0.f;
    if (gi < H && gj < W) {
      float s = 0.f;
      #pragma unroll
      for (int g = 0; g < 7; ++g)
        s += Epart[((size_t)g * B + b) * NIMG + gi * W + gj];
      v = expf(s * (1.f / C));
      if (r < 32 && cc < 32) E[(size_t)b * NIMG + gi * W + gj] = v;
    }
    tin[r][cc] = v;
  }
  __syncthreads();
  for (int idx = tid; idx < 39 * 32; idx += 256) {
    int r = idx >> 5, j = idx & 31;
    float s = 0.f;
    #pragma unroll
    for (int d = 0; d < 8; ++d) s += tin[r][j + d];
    hs[r][j] = s;
  }
  __syncthreads();
  for (int idx = tid; idx < 32 * 32; idx += 256) {
    int i = idx >> 5, j = idx & 31;
    int gi = i0 + i, gj = j0 + j;
    if (gi < HC && gj < WC) {
      float s = 0.f;
      #pragma unroll
      for (int d = 0; d < 8; ++d) s += hs[i + d][j];
      S[(size_t)b * NSP + gi * WC + gj] = s;
    }
  }
}

// ---------------------------------------------------------------------------
// y1_stats_nb: ONE 128-px chunk per block (grid 3062, no loop, no persistent
// acc). Body = R5-verified y1_stats math; reduce a0/a1 directly.
// ---------------------------------------------------------------------------
__global__ __launch_bounds__(256) void y1_stats_kernel(
    const unsigned short* __restrict__ p_t, const float* __restrict__ w1,
    float* __restrict__ stats) {
  __shared__ unsigned short Wl[64 * 64];
  const int tid = threadIdx.x, wave = tid >> 6, lane = tid & 63;
  for (int idx = tid; idx < 4096; idx += 256) {
    int o = idx >> 6, k = idx & 63;
    float v = (o < C && k < C) ? w1[o * C + k] : 0.f;
    *(unsigned short*)((char*)Wl + (o * 128 + ((2 * k) ^ ((o & 7) << 4)))) = f2bf(v);
  }
  __syncthreads();
  short8 afr[2][4];
  #pragma unroll
  for (int q = 0; q < 2; ++q)
    #pragma unroll
    for (int ks = 0; ks < 4; ++ks) {
      int row = q * 32 + (lane & 31), kb = ks * 16 + 8 * (lane >> 5);
      afr[q][ks] = *(const short8*)((const char*)Wl + row * 128 + ((2 * kb) ^ ((row & 7) << 4)));
    }
  const int h = lane >> 5;
  int col = blockIdx.x * 128 + wave * 32 + (lane & 31);
  bool cv = col < NPIX;
  size_t pofs = (size_t)(cv ? col : 0) * 8;
  short8 bfr[4];
  #pragma unroll
  for (int ks = 0; ks < 4; ++ks) {
    int g = ks * 2 + h;
    short8 bv = (short8){0, 0, 0, 0, 0, 0, 0, 0};
    if (g < 7 && cv) bv = *(const short8*)(p_t + (size_t)g * NPIX * 8 + pofs);
    bfr[ks] = bv;
  }
  float16 a0 = {}, a1 = {};
  #pragma unroll
  for (int ks = 0; ks < 4; ++ks) {
    a0 = __builtin_amdgcn_mfma_f32_32x32x16_bf16(afr[0][ks], bfr[ks], a0, 0, 0, 0);
    a1 = __builtin_amdgcn_mfma_f32_32x32x16_bf16(afr[1][ks], bfr[ks], a1, 0, 0, 0);
  }
  int bin = (blockIdx.x & 7) * 112;
  #pragma unroll
  for (int q = 0; q < 2; ++q)
    #pragma unroll
    for (int r = 0; r < 16; ++r) {
      float v1 = (q == 0) ? a0[r] : a1[r];
      float v2 = v1 * v1;
      #pragma unroll
      for (int off = 1; off < 32; off <<= 1) {
        v1 += __shfl_xor(v1, off);
        v2 += __shfl_xor(v2, off);
      }
      if ((lane & 31) == 0) {
        int row = 32 * q + (r & 3) + 8 * (r >> 2) + 4 * h;
        if (row < C) {
          atomicAdd(&stats[bin + row], v1);
          atomicAdd(&stats[bin + 56 + row], v2);
        }
      }
    }
}

// BN1 coefficients (R5-verified): af = g1/sqrt(var+eps), cf = be1 - af*mean_d
__global__ void bn1_final_kernel(const float* __restrict__ stats,
                                 const float* __restrict__ g1, const float* __restrict__ be1,
                                 float* __restrict__ ac) {
  int o = threadIdx.x;
  if (o >= C) return;
  float s1 = 0.f, s2 = 0.f;
  for (int bin = 0; bin < 8; ++bin) { s1 += stats[bin * 112 + o]; s2 += stats[bin * 112 + 56 + o]; }
  float m = s1 * (1.f / NPIX);
  float var = s2 * (1.f / NPIX) - m * m;
  float a = g1[o] * rsqrtf(var + BN_EPS);
  ac[o] = a;
  ac[C + o] = fmaf(-a, m, be1[o]);
}

// ---------------------------------------------------------------------------
// y2_nb: ONE 128-px chunk per block (grid 3062, no loop). Body = R5-verified.
// ---------------------------------------------------------------------------
__global__ __launch_bounds__(256) void y2_kernel(
    const unsigned short* __restrict__ p_t, const float* __restrict__ w1,
    const float* __restrict__ ac, const float* __restrict__ w2,
    float* __restrict__ y2, float* __restrict__ stats2) {
  __shared__ unsigned short Wl[64 * 64];
  __shared__ float af[64], cf[64], wf[64];
  const int tid = threadIdx.x, wave = tid >> 6, lane = tid & 63;
  for (int idx = tid; idx < 4096; idx += 256) {
    int o = idx >> 6, k = idx & 63;
    float v = (o < C && k < C) ? w1[o * C + k] : 0.f;
    *(unsigned short*)((char*)Wl + (o * 128 + ((2 * k) ^ ((o & 7) << 4)))) = f2bf(v);
  }
  if (tid < 64) {
    bool ok = tid < C;
    af[tid] = ok ? ac[tid] : 0.f;
    cf[tid] = ok ? ac[C + tid] : 0.f;
    wf[tid] = ok ? w2[tid] : 0.f;
  }
  __syncthreads();
  short8 afr[2][4];
  #pragma unroll
  for (int q = 0; q < 2; ++q)
    #pragma unroll
    for (int ks = 0; ks < 4; ++ks) {
      int row = q * 32 + (lane & 31), kb = ks * 16 + 8 * (lane >> 5);
      afr[q][ks] = *(const short8*)((const char*)Wl + row * 128 + ((2 * kb) ^ ((row & 7) << 4)));
    }
  const int h = lane >> 5;
  int col = blockIdx.x * 128 + wave * 32 + (lane & 31);
  bool cv = col < NPIX;
  size_t pofs = (size_t)(cv ? col : 0) * 8;
  short8 bfr[4];
  #pragma unroll
  for (int ks = 0; ks < 4; ++ks) {
    int g = ks * 2 + h;
    short8 bv = (short8){0, 0, 0, 0, 0, 0, 0, 0};
    if (g < 7 && cv) bv = *(const short8*)(p_t + (size_t)g * NPIX * 8 + pofs);
    bfr[ks] = bv;
  }
  float16 a0 = {}, a1 = {};
  #pragma unroll
  for (int ks = 0; ks < 4; ++ks) {
    a0 = __builtin_amdgcn_mfma_f32_32x32x16_bf16(afr[0][ks], bfr[ks], a0, 0, 0, 0);
    a1 = __builtin_amdgcn_mfma_f32_32x32x16_bf16(afr[1][ks], bfr[ks], a1, 0, 0, 0);
  }
  float ysum = 0.f;
  #pragma unroll
  for (int r = 0; r < 16; ++r) {
    int o0 = (r & 3) + 8 * (r >> 2) + 4 * h;
    ysum = fmaf(wf[o0], fmaxf(fmaf(af[o0], a0[r], cf[o0]), 0.f), ysum);
    int o1 = o0 + 32;
    ysum = fmaf(wf[o1], fmaxf(fmaf(af[o1], a1[r], cf[o1]), 0.f), ysum);
  }
  ysum += __shfl_xor(ysum, 32);
  float ss1 = 0.f, ss2 = 0.f;
  bool wr = cv && lane < 32;
  if (wr) {
    y2[col] = ysum;
    ss1 = ysum;
    ss2 = ysum * ysum;
  }
  #pragma unroll
  for (int off = 1; off < 64; off <<= 1) {
    ss1 += __shfl_xor(ss1, off);
    ss2 += __shfl_xor(ss2, off);
  }
  if (lane == 0) {
    atomicAdd(&stats2[(blockIdx.x & 63) * 2 + 0], ss1);
    atomicAdd(&stats2[(blockIdx.x & 63) * 2 + 1], ss2);
  }
}

__global__ void bn2_final_kernel(const float* __restrict__ stats2,
                                 const float* __restrict__ g2, const float* __restrict__ be2,
                                 float* __restrict__ a2c2) {
  int t = threadIdx.x;   // 64 threads
  float s1 = stats2[t * 2], s2 = stats2[t * 2 + 1];
  #pragma unroll
  for (int off = 32; off > 0; off >>= 1) {
    s1 += __shfl_down(s1, off);
    s2 += __shfl_down(s2, off);
  }
  if (t == 0) {
    float mean = s1 * (1.f / NPIX);
    float var  = s2 * (1.f / NPIX) - mean * mean;
    float a = g2[0] * rsqrtf(var + BN_EPS);
    a2c2[0] = a;
    a2c2[1] = fmaf(-a, mean, be2[0]);
  }
}

// ---------------------------------------------------------------------------
// r_pool (R5-verified, verbatim)
// ---------------------------------------------------------------------------
__global__ __launch_bounds__(256) void r_pool_kernel(
    const float* __restrict__ y2, const float* __restrict__ S,
    const float* __restrict__ a2c2, const float* __restrict__ E,
    float* __restrict__ cout, float* __restrict__ R) {
  __shared__ float tin[39][40];
  __shared__ float hs[39][33];
  const int b = blockIdx.z;
  const int i0 = blockIdx.y * 32, j0 = blockIdx.x * 32;
  const int tid = threadIdx.x;
  const float a2 = a2c2[0], c2 = a2c2[1];
  const float* y2b = y2 + (size_t)b * NSP;
  const float* Sb  = S + (size_t)b * NSP;
  float* cb = cout + (size_t)b * NSP;
  for (int idx = tid; idx < 39 * 39; idx += 256) {
    int r = idx / 39, cc = idx - r * 39;
    int gi = i0 + r - 7, gj = j0 + cc - 7;
    float t = 0.f;
    if (gi >= 0 && gi < HC && gj >= 0 && gj < WC) {
      float v = fmaxf(fmaf(a2, y2b[gi * WC + gj], c2), 0.f);
      t = v / Sb[gi * WC + gj];
      if (r >= 7 && cc >= 7) cb[gi * WC + gj] = v;
    }
    tin[r][cc] = t;
  }
  __syncthreads();
  for (int idx = tid; idx < 39 * 32; idx += 256) {
    int r = idx >> 5, j = idx & 31;
    float s = 0.f;
    #pragma unroll
    for (int d = 0; d < 8; ++d) s += tin[r][j + d];
    hs[r][j] = s;
  }
  __syncthreads();
  for (int idx = tid; idx < 32 * 32; idx += 256) {
    int i = idx >> 5, j = idx & 31;
    size_t gofs = (size_t)b * NIMG + (i0 + i) * W + (j0 + j);
    float s = 0.f;
    #pragma unroll
    for (int d = 0; d < 8; ++d) s += hs[i + d][j];
    R[gofs] = E[gofs] * s;
  }
}

extern "C" void kernel_launch(void* const* d_in, const int* in_sizes, int n_in,
                              void* d_out, int out_size, void* d_ws, size_t ws_size,
                              hipStream_t stream) {
  const float* x   = (const float*)d_in[0];
  const float* w1  = (const float*)d_in[1];
  const float* w2  = (const float*)d_in[3];
  const float* g1  = (const float*)d_in[5];
  const float* be1 = (const float*)d_in[6];
  const float* g2  = (const float*)d_in[7];
  const float* be2 = (const float*)d_in[8];

  float* out_c = (float*)d_out;          // C_out: NPIX floats
  float* out_r = out_c + NPIX;           // R: NM floats

  // workspace: p_t 43.9 MB + Epart 11.5 + E 1.6 + S/y2 0.8 + small ≈ 58 MB
  unsigned short* p_t = (unsigned short*)d_ws;          // [7][NPIX][8] bf16
  float* fbase = (float*)(p_t + (size_t)7 * NPIX * 8);
  size_t off = 0;
  float* Epart  = fbase + off; off += (size_t)7 * NM;
  float* E      = fbase + off; off += NM;
  float* Sarr   = fbase + off; off += NPIX;
  float* y2     = fbase + off; off += NPIX;
  float* stats  = fbase + off; off += 8 * 112;
  float* stats2 = fbase + off; off += 128;
  float* ac     = fbase + off; off += 112;
  float* a2c2   = fbase + off; off += 2;

  hipMemsetAsync(stats, 0, (8 * 112 + 128) * sizeof(float), stream);

  pool32_kernel<<<100 * B * 7, 256, 0, stream>>>(x, Epart, p_t);

  dim3 sg(10, 10, B);
  se_pool_kernel<<<sg, 256, 0, stream>>>(Epart, E, Sarr);

  y1_stats_kernel<<<NCHUNK3, 256, 0, stream>>>(p_t, w1, stats);
  bn1_final_kernel<<<1, 64, 0, stream>>>(stats, g1, be1, ac);
  y2_kernel<<<NCHUNK3, 256, 0, stream>>>(p_t, w1, ac, w2, y2, stats2);
  bn2_final_kernel<<<1, 64, 0, stream>>>(stats2, g2, be2, a2c2);

  dim3 rg(10, 10, B);
  r_pool_kernel<<<rg, 256, 0, stream>>>(y2, Sarr, a2c2, E, out_c, out_r);
}

// Round 11
// 120.308 us; speedup vs baseline: 4.4919x; 4.4919x over previous
//
#include <hip/hip_runtime.h>
#include <math.h>

#define B 4
#define C 56
#define H 320
#define W 320
#define HC 313
#define WC 313
#define NIMG (H*W)          // 102400
#define NSP  (HC*WC)        // 97969
#define NPIX (B*NSP)        // 391876
#define NM   (B*NIMG)       // 409600
#define BN_EPS 1e-5f
#define NGRID 512

// pool32 tile: 32x32 interior, 39x39 halo
#define PHR 39
#define PNH (PHR*PHR)       // 1521

typedef __attribute__((ext_vector_type(8))) short short8;
typedef __attribute__((ext_vector_type(16))) float float16;

__device__ __forceinline__ unsigned short f2bf(float v) {
  unsigned int u = __float_as_uint(v);
  return (unsigned short)((u + 0x7fffu + ((u >> 16) & 1u)) >> 16);
}

// ---------------------------------------------------------------------------
// pool32 (R5-verified, verbatim): one (32x32 tile, b, 8-ch group) per block.
// p_t layout: [g][pix 0..NPIX)[8 ch] bf16, pix = b*NSP + gi*WC + gj (dense).
// ---------------------------------------------------------------------------
__global__ __launch_bounds__(256) void pool32_kernel(
    const float* __restrict__ x, float* __restrict__ Epart,
    unsigned short* __restrict__ p_t) {
  __shared__ float tin[PHR][40];
  __shared__ float hs[PHR][32];
  __shared__ unsigned short Pt[8][1024];
  const int tid = threadIdx.x;
  int bid = blockIdx.x;
  const int g = bid % 7; bid /= 7;
  const int b = bid & 3; bid >>= 2;
  const int ty = bid / 10, tx = bid - (bid / 10) * 10;
  const int i0 = ty * 32, j0 = tx * 32;
  const float* xg = x + ((size_t)b * C + g * 8) * NIMG;

  float esum[6];
  #pragma unroll
  for (int k = 0; k < 6; ++k) esum[k] = 0.f;

  float cur[6], nxt[6];
  {
    const float* xp = xg;
    #pragma unroll
    for (int k = 0; k < 6; ++k) {
      int idx = tid + k * 256;
      int r = idx / PHR, cc = idx - r * PHR;
      int gi = i0 + r, gj = j0 + cc;
      cur[k] = (idx < PNH && gi < H && gj < W) ? xp[gi * W + gj] : 0.f;
    }
  }

  #pragma unroll
  for (int c = 0; c < 8; ++c) {
    #pragma unroll
    for (int k = 0; k < 6; ++k) {
      int idx = tid + k * 256;
      if (idx < PNH) {
        int r = idx / PHR, cc = idx - r * PHR;
        tin[r][cc] = cur[k];
        if (r < 32 && cc < 32) esum[k] += cur[k];
      }
    }
    __syncthreads();
    if (c < 7) {
      const float* xp = xg + (size_t)(c + 1) * NIMG;
      #pragma unroll
      for (int k = 0; k < 6; ++k) {
        int idx = tid + k * 256;
        int r = idx / PHR, cc = idx - r * PHR;
        int gi = i0 + r, gj = j0 + cc;
        nxt[k] = (idx < PNH && gi < H && gj < W) ? xp[gi * W + gj] : 0.f;
      }
    }
    #pragma unroll
    for (int it = 0; it < 5; ++it) {
      int idx = tid + it * 256;
      if (idx < PHR * 32) {
        int r = idx >> 5, j = idx & 31;
        float s = 0.f;
        #pragma unroll
        for (int d = 0; d < 8; ++d) s += tin[r][j + d];
        hs[r][j] = s;
      }
    }
    __syncthreads();
    #pragma unroll
    for (int it = 0; it < 4; ++it) {
      int idx = tid + it * 256;
      int i = idx >> 5, j = idx & 31;
      float s = 0.f;
      #pragma unroll
      for (int d = 0; d < 8; ++d) s += hs[i + d][j];
      Pt[c][idx] = f2bf(s * (1.f / 64.f));
    }
    #pragma unroll
    for (int k = 0; k < 6; ++k) cur[k] = nxt[k];
  }
  __syncthreads();   // Pt complete

  float* Eb = Epart + ((size_t)g * B + b) * NIMG;
  #pragma unroll
  for (int k = 0; k < 6; ++k) {
    int idx = tid + k * 256;
    if (idx < PNH) {
      int r = idx / PHR, cc = idx - r * PHR;
      if (r < 32 && cc < 32) Eb[(i0 + r) * W + (j0 + cc)] = esum[k];
    }
  }

  unsigned short* pg = p_t + (size_t)g * NPIX * 8;
  #pragma unroll
  for (int k = 0; k < 4; ++k) {
    int idx = tid + k * 256;
    int i = idx >> 5, j = idx & 31;
    int gi = i0 + i, gj = j0 + j;
    if (gi < HC && gj < WC) {
      unsigned short t8[8];
      #pragma unroll
      for (int c2 = 0; c2 < 8; ++c2) t8[c2] = Pt[c2][idx];
      *(short8*)(pg + ((size_t)b * NSP + gi * WC + gj) * 8) = *(short8*)t8;
    }
  }
}

// ---------------------------------------------------------------------------
// se_pool (R5-verified, verbatim)
// ---------------------------------------------------------------------------
__global__ __launch_bounds__(256) void se_pool_kernel(
    const float* __restrict__ Epart, float* __restrict__ E, float* __restrict__ S) {
  __shared__ float tin[39][40];
  __shared__ float hs[39][33];
  const int b = blockIdx.z;
  const int i0 = blockIdx.y * 32, j0 = blockIdx.x * 32;
  const int tid = threadIdx.x;
  for (int idx = tid; idx < 39 * 39; idx += 256) {
    int r = idx / 39, cc = idx - r * 39;
    int gi = i0 + r, gj = j0 + cc;
    float v = 0.f;
    if (gi < H && gj < W) {
      float s = 0.f;
      #pragma unroll
      for (int g = 0; g < 7; ++g)
        s += Epart[((size_t)g * B + b) * NIMG + gi * W + gj];
      v = expf(s * (1.f / C));
      if (r < 32 && cc < 32) E[(size_t)b * NIMG + gi * W + gj] = v;
    }
    tin[r][cc] = v;
  }
  __syncthreads();
  for (int idx = tid; idx < 39 * 32; idx += 256) {
    int r = idx >> 5, j = idx & 31;
    float s = 0.f;
    #pragma unroll
    for (int d = 0; d < 8; ++d) s += tin[r][j + d];
    hs[r][j] = s;
  }
  __syncthreads();
  for (int idx = tid; idx < 32 * 32; idx += 256) {
    int i = idx >> 5, j = idx & 31;
    int gi = i0 + i, gj = j0 + j;
    if (gi < HC && gj < WC) {
      float s = 0.f;
      #pragma unroll
      for (int d = 0; d < 8; ++d) s += hs[i + d][j];
      S[(size_t)b * NSP + gi * WC + gj] = s;
    }
  }
}

// ---------------------------------------------------------------------------
// y1_stats: R5-verified main loop (512 blocks, 6 chunks, register s1/s2).
// NEW flush: raw accumulators -> LDS (plain), 56-thread cross-wave reduce,
// ONE plain 112-float store per block to ypart. No atomics, no shuffles.
// ---------------------------------------------------------------------------
__global__ __launch_bounds__(256) void y1_stats_kernel(
    const unsigned short* __restrict__ p_t, const float* __restrict__ w1,
    float* __restrict__ ypart) {
  __shared__ unsigned short Wl[64 * 64];
  __shared__ float red[4][32][64];   // 32 KB, used only in flush
  const int tid = threadIdx.x, wave = tid >> 6, lane = tid & 63;
  for (int idx = tid; idx < 4096; idx += 256) {
    int o = idx >> 6, k = idx & 63;
    float v = (o < C && k < C) ? w1[o * C + k] : 0.f;
    *(unsigned short*)((char*)Wl + (o * 128 + ((2 * k) ^ ((o & 7) << 4)))) = f2bf(v);
  }
  __syncthreads();
  short8 afr[2][4];
  #pragma unroll
  for (int q = 0; q < 2; ++q)
    #pragma unroll
    for (int ks = 0; ks < 4; ++ks) {
      int row = q * 32 + (lane & 31), kb = ks * 16 + 8 * (lane >> 5);
      afr[q][ks] = *(const short8*)((const char*)Wl + row * 128 + ((2 * kb) ^ ((row & 7) << 4)));
    }
  float s1[2][16], s2[2][16];
  #pragma unroll
  for (int q = 0; q < 2; ++q)
    #pragma unroll
    for (int r = 0; r < 16; ++r) { s1[q][r] = 0.f; s2[q][r] = 0.f; }

  const int h = lane >> 5;
  const int nchunk = (NPIX + 127) / 128;   // 3062
  for (int ch = blockIdx.x; ch < nchunk; ch += NGRID) {
    int col = ch * 128 + wave * 32 + (lane & 31);
    bool cv = col < NPIX;
    size_t pofs = (size_t)(cv ? col : 0) * 8;
    short8 bfr[4];
    #pragma unroll
    for (int ks = 0; ks < 4; ++ks) {
      int g = ks * 2 + h;
      short8 bv = (short8){0, 0, 0, 0, 0, 0, 0, 0};
      if (g < 7 && cv) bv = *(const short8*)(p_t + (size_t)g * NPIX * 8 + pofs);
      bfr[ks] = bv;
    }
    float16 a0 = {}, a1 = {};
    #pragma unroll
    for (int ks = 0; ks < 4; ++ks) {
      a0 = __builtin_amdgcn_mfma_f32_32x32x16_bf16(afr[0][ks], bfr[ks], a0, 0, 0, 0);
      a1 = __builtin_amdgcn_mfma_f32_32x32x16_bf16(afr[1][ks], bfr[ks], a1, 0, 0, 0);
    }
    #pragma unroll
    for (int r = 0; r < 16; ++r) {
      s1[0][r] += a0[r]; s2[0][r] = fmaf(a0[r], a0[r], s2[0][r]);
      s1[1][r] += a1[r]; s2[1][r] = fmaf(a1[r], a1[r], s2[1][r]);
    }
  }
  // flush: pass 0 = sums, pass 1 = sumsq
  for (int pass = 0; pass < 2; ++pass) {
    __syncthreads();   // red free (prev pass reads / Wl reads done)
    #pragma unroll
    for (int q = 0; q < 2; ++q)
      #pragma unroll
      for (int r = 0; r < 16; ++r)
        red[wave][q * 16 + r][lane] = pass ? s2[q][r] : s1[q][r];
    __syncthreads();
    if (tid < C) {
      // output channel row = tid; D-layout: row=(reg&3)+8*(reg>>2)+4*(lane>>5)
      int row = tid, q = row >> 5, rr = row & 31;
      int hh = (rr >> 2) & 1, reg = (rr & 3) | ((rr >> 3) << 2);
      float s = 0.f;
      #pragma unroll
      for (int w = 0; w < 4; ++w)
        #pragma unroll
        for (int cl = 0; cl < 32; ++cl)
          s += red[w][q * 16 + reg][32 * hh + cl];
      ypart[blockIdx.x * 112 + pass * 56 + row] = s;
    }
  }
}

// ---------------------------------------------------------------------------
// ypart_bn1: reduce 512 partials (plain loads) + BN1 coefficients inline.
// af = g1/sqrt(var+eps), cf = be1 - af*mean_d  (b1 cancels)
// ---------------------------------------------------------------------------
__global__ void ypart_bn1_kernel(const float* __restrict__ ypart,
                                 const float* __restrict__ g1, const float* __restrict__ be1,
                                 float* __restrict__ ac) {
  __shared__ float sums[112];
  int t = threadIdx.x;   // 128 threads
  if (t < 112) {
    float s0 = 0.f, s1 = 0.f, s2 = 0.f, s3 = 0.f;
    #pragma unroll 4
    for (int b = 0; b < NGRID; b += 4) {
      s0 += ypart[(b + 0) * 112 + t];
      s1 += ypart[(b + 1) * 112 + t];
      s2 += ypart[(b + 2) * 112 + t];
      s3 += ypart[(b + 3) * 112 + t];
    }
    sums[t] = (s0 + s1) + (s2 + s3);
  }
  __syncthreads();
  if (t < C) {
    float m = sums[t] * (1.f / NPIX);
    float var = sums[56 + t] * (1.f / NPIX) - m * m;
    float a = g1[t] * rsqrtf(var + BN_EPS);
    ac[t] = a;
    ac[C + t] = fmaf(-a, m, be1[t]);
  }
}

// ---------------------------------------------------------------------------
// y2 (R5-verified, verbatim): d2 = w2 . relu(af*(W1 p) + cf) per pixel (MFMA
// from p_t); BN2 stats binned (2 atomics/block — negligible).
// ---------------------------------------------------------------------------
__global__ __launch_bounds__(256) void y2_kernel(
    const unsigned short* __restrict__ p_t, const float* __restrict__ w1,
    const float* __restrict__ ac, const float* __restrict__ w2,
    float* __restrict__ y2, float* __restrict__ stats2) {
  __shared__ unsigned short Wl[64 * 64];
  __shared__ float af[64], cf[64], wf[64];
  const int tid = threadIdx.x, wave = tid >> 6, lane = tid & 63;
  for (int idx = tid; idx < 4096; idx += 256) {
    int o = idx >> 6, k = idx & 63;
    float v = (o < C && k < C) ? w1[o * C + k] : 0.f;
    *(unsigned short*)((char*)Wl + (o * 128 + ((2 * k) ^ ((o & 7) << 4)))) = f2bf(v);
  }
  if (tid < 64) {
    bool ok = tid < C;
    af[tid] = ok ? ac[tid] : 0.f;
    cf[tid] = ok ? ac[C + tid] : 0.f;
    wf[tid] = ok ? w2[tid] : 0.f;
  }
  __syncthreads();
  short8 afr[2][4];
  #pragma unroll
  for (int q = 0; q < 2; ++q)
    #pragma unroll
    for (int ks = 0; ks < 4; ++ks) {
      int row = q * 32 + (lane & 31), kb = ks * 16 + 8 * (lane >> 5);
      afr[q][ks] = *(const short8*)((const char*)Wl + row * 128 + ((2 * kb) ^ ((row & 7) << 4)));
    }
  const int h = lane >> 5;
  float ss1 = 0.f, ss2 = 0.f;
  const int nchunk = (NPIX + 127) / 128;
  for (int ch = blockIdx.x; ch < nchunk; ch += NGRID) {
    int col = ch * 128 + wave * 32 + (lane & 31);
    bool cv = col < NPIX;
    size_t pofs = (size_t)(cv ? col : 0) * 8;
    short8 bfr[4];
    #pragma unroll
    for (int ks = 0; ks < 4; ++ks) {
      int g = ks * 2 + h;
      short8 bv = (short8){0, 0, 0, 0, 0, 0, 0, 0};
      if (g < 7 && cv) bv = *(const short8*)(p_t + (size_t)g * NPIX * 8 + pofs);
      bfr[ks] = bv;
    }
    float16 a0 = {}, a1 = {};
    #pragma unroll
    for (int ks = 0; ks < 4; ++ks) {
      a0 = __builtin_amdgcn_mfma_f32_32x32x16_bf16(afr[0][ks], bfr[ks], a0, 0, 0, 0);
      a1 = __builtin_amdgcn_mfma_f32_32x32x16_bf16(afr[1][ks], bfr[ks], a1, 0, 0, 0);
    }
    float ysum = 0.f;
    #pragma unroll
    for (int r = 0; r < 16; ++r) {
      int o0 = (r & 3) + 8 * (r >> 2) + 4 * h;
      ysum = fmaf(wf[o0], fmaxf(fmaf(af[o0], a0[r], cf[o0]), 0.f), ysum);
      int o1 = o0 + 32;
      ysum = fmaf(wf[o1], fmaxf(fmaf(af[o1], a1[r], cf[o1]), 0.f), ysum);
    }
    ysum += __shfl_xor(ysum, 32);
    bool wr = cv && lane < 32;
    if (wr) {
      y2[col] = ysum;
      ss1 += ysum;
      ss2 = fmaf(ysum, ysum, ss2);
    }
  }
  #pragma unroll
  for (int off = 1; off < 64; off <<= 1) {
    ss1 += __shfl_xor(ss1, off);
    ss2 += __shfl_xor(ss2, off);
  }
  if (lane == 0) {
    atomicAdd(&stats2[(blockIdx.x & 63) * 2 + 0], ss1);
    atomicAdd(&stats2[(blockIdx.x & 63) * 2 + 1], ss2);
  }
}

__global__ void bn2_final_kernel(const float* __restrict__ stats2,
                                 const float* __restrict__ g2, const float* __restrict__ be2,
                                 float* __restrict__ a2c2) {
  int t = threadIdx.x;   // 64 threads
  float s1 = stats2[t * 2], s2 = stats2[t * 2 + 1];
  #pragma unroll
  for (int off = 32; off > 0; off >>= 1) {
    s1 += __shfl_down(s1, off);
    s2 += __shfl_down(s2, off);
  }
  if (t == 0) {
    float mean = s1 * (1.f / NPIX);
    float var  = s2 * (1.f / NPIX) - mean * mean;
    float a = g2[0] * rsqrtf(var + BN_EPS);
    a2c2[0] = a;
    a2c2[1] = fmaf(-a, mean, be2[0]);
  }
}

// ---------------------------------------------------------------------------
// r_pool (R5-verified, verbatim)
// ---------------------------------------------------------------------------
__global__ __launch_bounds__(256) void r_pool_kernel(
    const float* __restrict__ y2, const float* __restrict__ S,
    const float* __restrict__ a2c2, const float* __restrict__ E,
    float* __restrict__ cout, float* __restrict__ R) {
  __shared__ float tin[39][40];
  __shared__ float hs[39][33];
  const int b = blockIdx.z;
  const int i0 = blockIdx.y * 32, j0 = blockIdx.x * 32;
  const int tid = threadIdx.x;
  const float a2 = a2c2[0], c2 = a2c2[1];
  const float* y2b = y2 + (size_t)b * NSP;
  const float* Sb  = S + (size_t)b * NSP;
  float* cb = cout + (size_t)b * NSP;
  for (int idx = tid; idx < 39 * 39; idx += 256) {
    int r = idx / 39, cc = idx - r * 39;
    int gi = i0 + r - 7, gj = j0 + cc - 7;
    float t = 0.f;
    if (gi >= 0 && gi < HC && gj >= 0 && gj < WC) {
      float v = fmaxf(fmaf(a2, y2b[gi * WC + gj], c2), 0.f);
      t = v / Sb[gi * WC + gj];
      if (r >= 7 && cc >= 7) cb[gi * WC + gj] = v;
    }
    tin[r][cc] = t;
  }
  __syncthreads();
  for (int idx = tid; idx < 39 * 32; idx += 256) {
    int r = idx >> 5, j = idx & 31;
    float s = 0.f;
    #pragma unroll
    for (int d = 0; d < 8; ++d) s += tin[r][j + d];
    hs[r][j] = s;
  }
  __syncthreads();
  for (int idx = tid; idx < 32 * 32; idx += 256) {
    int i = idx >> 5, j = idx & 31;
    size_t gofs = (size_t)b * NIMG + (i0 + i) * W + (j0 + j);
    float s = 0.f;
    #pragma unroll
    for (int d = 0; d < 8; ++d) s += hs[i + d][j];
    R[gofs] = E[gofs] * s;
  }
}

extern "C" void kernel_launch(void* const* d_in, const int* in_sizes, int n_in,
                              void* d_out, int out_size, void* d_ws, size_t ws_size,
                              hipStream_t stream) {
  const float* x   = (const float*)d_in[0];
  const float* w1  = (const float*)d_in[1];
  const float* w2  = (const float*)d_in[3];
  const float* g1  = (const float*)d_in[5];
  const float* be1 = (const float*)d_in[6];
  const float* g2  = (const float*)d_in[7];
  const float* be2 = (const float*)d_in[8];

  float* out_c = (float*)d_out;          // C_out: NPIX floats
  float* out_r = out_c + NPIX;           // R: NM floats

  // workspace: p_t 43.9 MB + Epart 11.5 + E 1.6 + S/y2 0.8 + ypart 0.23 ≈ 58 MB
  unsigned short* p_t = (unsigned short*)d_ws;          // [7][NPIX][8] bf16
  float* fbase = (float*)(p_t + (size_t)7 * NPIX * 8);
  size_t off = 0;
  float* Epart  = fbase + off; off += (size_t)7 * NM;
  float* E      = fbase + off; off += NM;
  float* Sarr   = fbase + off; off += NPIX;
  float* y2     = fbase + off; off += NPIX;
  float* ypart  = fbase + off; off += NGRID * 112;
  float* stats2 = fbase + off; off += 128;
  float* ac     = fbase + off; off += 112;
  float* a2c2   = fbase + off; off += 2;

  hipMemsetAsync(stats2, 0, 128 * sizeof(float), stream);

  pool32_kernel<<<100 * B * 7, 256, 0, stream>>>(x, Epart, p_t);

  dim3 sg(10, 10, B);
  se_pool_kernel<<<sg, 256, 0, stream>>>(Epart, E, Sarr);

  y1_stats_kernel<<<NGRID, 256, 0, stream>>>(p_t, w1, ypart);
  ypart_bn1_kernel<<<1, 128, 0, stream>>>(ypart, g1, be1, ac);
  y2_kernel<<<NGRID, 256, 0, stream>>>(p_t, w1, ac, w2, y2, stats2);
  bn2_final_kernel<<<1, 64, 0, stream>>>(stats2, g2, be2, a2c2);

  dim3 rg(10, 10, B);
  r_pool_kernel<<<rg, 256, 0, stream>>>(y2, Sarr, a2c2, E, out_c, out_r);
}